// Round 1
// baseline (477.549 us; speedup 1.0000x reference)
//
#include <hip/hip_runtime.h>
#include <cstdint>
#include <cstddef>

#define NT 256
#define DFEAT 128
#define SCAN_ELEMS 1024
#define GEMM_ROWS 128    // rows per gemm block (4 waves x 32 rows)
#define BPAD 136         // padded LDS k-stride (ushorts) for W^T tiles

typedef __attribute__((ext_vector_type(8))) short s8v;
typedef __attribute__((ext_vector_type(4))) float f32x4;

__device__ inline ushort f2bf(float f) {           // RNE fp32 -> bf16
  uint32_t u = __float_as_uint(f);
  u += 0x7fffu + ((u >> 16) & 1u);
  return (ushort)(u >> 16);
}
__device__ inline void accw_bf4(uint2 v, float w, float& a0, float& a1, float& a2, float& a3) {
  a0 = fmaf(w, __uint_as_float(v.x << 16), a0);
  a1 = fmaf(w, __uint_as_float(v.x & 0xffff0000u), a1);
  a2 = fmaf(w, __uint_as_float(v.y << 16), a2);
  a3 = fmaf(w, __uint_as_float(v.y & 0xffff0000u), a3);
}

// ---------- zero int array ----------
__global__ void zero_k(int* __restrict__ p, int n) {
  int i = blockIdx.x * NT + threadIdx.x;
  if (i < n) p[i] = 0;
}

// ---------- histogram of dst, both graphs in one dispatch ----------
__global__ void hist2_k(const int* __restrict__ e_dst, int E,
                        const int* __restrict__ c_dst, int EC,
                        int* __restrict__ cnt_c, int* __restrict__ cnt_t) {
  int i = blockIdx.x * NT + threadIdx.x;
  if (i < E) atomicAdd(&cnt_c[e_dst[i]], 1);
  else if (i < E + EC) atomicAdd(&cnt_t[c_dst[i - E]], 1);
}

// ---------- scan pass A ----------
__global__ __launch_bounds__(NT) void scan_partial_k(
    const int* __restrict__ cnt_c, const int* __restrict__ cnt_t, int n,
    int* __restrict__ bsum, int nb_c) {
  int isT = blockIdx.x >= nb_c;
  const int* cnt = isT ? cnt_t : cnt_c;
  int b = isT ? blockIdx.x - nb_c : blockIdx.x;
  int base = b * SCAN_ELEMS + threadIdx.x * 4;

  int s = 0;
  if (base + 3 < n) {
    int4 v = *(const int4*)&cnt[base];
    s = v.x + v.y + v.z + v.w;
  } else {
    for (int j = 0; j < 4; j++) if (base + j < n) s += cnt[base + j];
  }
  for (int off = 32; off > 0; off >>= 1) s += __shfl_down(s, off, 64);
  __shared__ int ws[4];
  int lane = threadIdx.x & 63, w = threadIdx.x >> 6;
  if (lane == 0) ws[w] = s;
  __syncthreads();
  if (threadIdx.x == 0) bsum[blockIdx.x] = ws[0] + ws[1] + ws[2] + ws[3];
}

// ---------- scan pass B ----------
__global__ __launch_bounds__(NT) void scan_offsets_k(
    int* __restrict__ bsum, int nb_c, int nb_t,
    int* __restrict__ rp_c, int* __restrict__ rp_t, int n) {
  int seg_off = (blockIdx.x == 0) ? 0 : nb_c;
  int nb = (blockIdx.x == 0) ? nb_c : nb_t;
  int* rp = (blockIdx.x == 0) ? rp_c : rp_t;

  __shared__ int ls[NT];
  int t = threadIdx.x;
  int v = (t < nb) ? bsum[seg_off + t] : 0;
  ls[t] = v;
  __syncthreads();
  for (int off = 1; off < NT; off <<= 1) {
    int u = (t >= off) ? ls[t - off] : 0;
    __syncthreads();
    ls[t] += u;
    __syncthreads();
  }
  if (t < nb) bsum[seg_off + t] = ls[t] - v;
  if (t == nb - 1) rp[n] = ls[t];
}

// ---------- scan pass C: rowptr out; also zeroes cnt (becomes fill cursor) ----------
__global__ __launch_bounds__(NT) void scan_final_k(
    int* __restrict__ cnt_c, int* __restrict__ cnt_t, int n,
    const int* __restrict__ bsum, int nb_c,
    int* __restrict__ rp_c, int* __restrict__ rp_t) {
  int isT = blockIdx.x >= nb_c;
  int* cnt = isT ? cnt_t : cnt_c;
  int* rp = isT ? rp_t : rp_c;
  int b = isT ? blockIdx.x - nb_c : blockIdx.x;
  int offset = bsum[blockIdx.x];
  int base = b * SCAN_ELEMS + threadIdx.x * 4;

  int4 v = make_int4(0, 0, 0, 0);
  if (base + 3 < n) v = *(const int4*)&cnt[base];
  else { if (base + 0 < n) v.x = cnt[base + 0];
         if (base + 1 < n) v.y = cnt[base + 1];
         if (base + 2 < n) v.z = cnt[base + 2];
         if (base + 3 < n) v.w = cnt[base + 3]; }
  int tsum = v.x + v.y + v.z + v.w;

  __shared__ int ls[NT];
  int t = threadIdx.x;
  ls[t] = tsum;
  __syncthreads();
  for (int off = 1; off < NT; off <<= 1) {
    int u = (t >= off) ? ls[t - off] : 0;
    __syncthreads();
    ls[t] += u;
    __syncthreads();
  }
  int excl = offset + ls[t] - tsum;

  int4 o;
  o.x = excl;
  o.y = o.x + v.x;
  o.z = o.y + v.y;
  o.w = o.z + v.z;
  if (base + 3 < n) {
    *(int4*)&rp[base] = o;
    *(int4*)&cnt[base] = make_int4(0, 0, 0, 0);   // cursor reset
  } else {
    if (base + 0 < n) { rp[base + 0] = o.x; cnt[base + 0] = 0; }
    if (base + 1 < n) { rp[base + 1] = o.y; cnt[base + 1] = 0; }
    if (base + 2 < n) { rp[base + 2] = o.z; cnt[base + 2] = 0; }
    if (base + 3 < n) { rp[base + 3] = o.w; cnt[base + 3] = 0; }
  }
}

// ---------- fill CSR, both graphs in one dispatch ----------
__global__ void fill2_k(const int* __restrict__ e_src, const int* __restrict__ e_dst, int E,
                        const int* __restrict__ c_src, const int* __restrict__ c_dst, int EC,
                        const int* __restrict__ rp_c, int* __restrict__ cur_c, int* __restrict__ csr_c,
                        const int* __restrict__ rp_t, int* __restrict__ cur_t, int* __restrict__ csr_t) {
  int i = blockIdx.x * NT + threadIdx.x;
  if (i < E) {
    int d = e_dst[i];
    csr_c[rp_c[d] + atomicAdd(&cur_c[d], 1)] = e_src[i];
  } else if (i < E + EC) {
    int j = i - E;
    int d = c_dst[j];
    csr_t[rp_t[d] + atomicAdd(&cur_t[d], 1)] = c_src[j];
  }
}

// ---------- dinv ----------
__global__ void dinv_k(const int* __restrict__ rp_c, float* __restrict__ dc,
                       const int* __restrict__ rp_t, float* __restrict__ dt, int n) {
  int i = blockIdx.x * NT + threadIdx.x;
  if (i < n) {
    dc[i] = rsqrtf((float)(rp_c[i + 1] - rp_c[i] + 1));
    dt[i] = rsqrtf((float)(rp_t[i + 1] - rp_t[i] + 1));
  }
}

// ---------- x fp32 -> bf16 ----------
__global__ void convx_k(const float* __restrict__ x, ushort* __restrict__ xh, int total4) {
  int i = blockIdx.x * NT + threadIdx.x;
  if (i < total4) {
    float4 v = ((const float4*)x)[i];
    ushort4 o;
    o.x = f2bf(v.x); o.y = f2bf(v.y); o.z = f2bf(v.z); o.w = f2bf(v.w);
    ((ushort4*)xh)[i] = o;
  }
}

// ---------- W fp32 [l][k][c] -> bf16 transposed wT[l][c][k] ----------
__global__ void convw_k(const float* __restrict__ Wc, const float* __restrict__ Wt,
                        ushort* __restrict__ wT) {
  int gid = blockIdx.x * NT + threadIdx.x;
  int l = gid >> 14, rem = gid & 16383;
  int c = rem >> 7, k = rem & 127;
  const float* W = (l < 4) ? (Wc + (size_t)l * 16384) : (Wt + (size_t)(l - 4) * 16384);
  wT[gid] = f2bf(W[k * DFEAT + c]);
}

// ---------- weighted gather: a += dinv[s] * x[s] over CSR neighbors ----------
__device__ inline void gather_w(const ushort* __restrict__ t, const int* __restrict__ rp,
                                const int* __restrict__ cs, const float* __restrict__ dinv,
                                int node, int lane, int c4,
                                float& a0, float& a1, float& a2, float& a3) {
  int s0 = rp[node], s1 = rp[node + 1];
  for (int p = s0; p < s1; p += 32) {
    int mm = min(32, s1 - p);
    int sv = 0; float wv = 0.f;
    if (lane < mm) { sv = cs[p + lane]; wv = dinv[sv]; }
    int k = 0;
    for (; k + 4 <= mm; k += 4) {
      int sA = __shfl(sv, k, 32);
      int sB = __shfl(sv, k + 1, 32);
      int sC = __shfl(sv, k + 2, 32);
      int sD = __shfl(sv, k + 3, 32);
      float wA = __shfl(wv, k, 32);
      float wB = __shfl(wv, k + 1, 32);
      float wC = __shfl(wv, k + 2, 32);
      float wD = __shfl(wv, k + 3, 32);
      uint2 vA = *(const uint2*)&t[(size_t)sA * DFEAT + c4];
      uint2 vB = *(const uint2*)&t[(size_t)sB * DFEAT + c4];
      uint2 vC = *(const uint2*)&t[(size_t)sC * DFEAT + c4];
      uint2 vD = *(const uint2*)&t[(size_t)sD * DFEAT + c4];
      accw_bf4(vA, wA, a0, a1, a2, a3);
      accw_bf4(vB, wB, a0, a1, a2, a3);
      accw_bf4(vC, wC, a0, a1, a2, a3);
      accw_bf4(vD, wD, a0, a1, a2, a3);
    }
    for (; k < mm; k++) {
      int s = __shfl(sv, k, 32);
      float w = __shfl(wv, k, 32);
      accw_bf4(*(const uint2*)&t[(size_t)s * DFEAT + c4], w, a0, a1, a2, a3);
    }
  }
}

// ---------- aggregate-first: both graphs gather from SAME x, per-src dinv weight ----------
// agg_c[v] = bf16( dinv_c[v] * ( dinv_c[v]*x[v] + sum_{s in Nc(v)} dinv_c[s]*x[s] ) )
__global__ __launch_bounds__(256) void aggregate2_k(
    const ushort* __restrict__ xh,
    const int* __restrict__ rpc, const int* __restrict__ csc,
    const int* __restrict__ rpt, const int* __restrict__ cst,
    const float* __restrict__ dc_, const float* __restrict__ dt_,
    ushort* __restrict__ aggc, ushort* __restrict__ aggt, int n) {
  int node = blockIdx.x * 8 + (threadIdx.x >> 5);
  if (node >= n) return;
  int lane = threadIdx.x & 31;
  int c4 = lane << 2;

  float dc = dc_[node], dt = dt_[node];
  uint2 sv = *(const uint2*)&xh[(size_t)node * DFEAT + c4];
  float x0 = __uint_as_float(sv.x << 16);
  float x1 = __uint_as_float(sv.x & 0xffff0000u);
  float x2 = __uint_as_float(sv.y << 16);
  float x3 = __uint_as_float(sv.y & 0xffff0000u);

  float a0 = dc * x0, a1 = dc * x1, a2 = dc * x2, a3 = dc * x3;
  float b0 = dt * x0, b1 = dt * x1, b2 = dt * x2, b3 = dt * x3;

  gather_w(xh, rpc, csc, dc_, node, lane, c4, a0, a1, a2, a3);
  gather_w(xh, rpt, cst, dt_, node, lane, c4, b0, b1, b2, b3);

  ushort4 ha, hb;
  ha.x = f2bf(dc * a0); ha.y = f2bf(dc * a1); ha.z = f2bf(dc * a2); ha.w = f2bf(dc * a3);
  hb.x = f2bf(dt * b0); hb.y = f2bf(dt * b1); hb.z = f2bf(dt * b2); hb.w = f2bf(dt * b3);
  *(ushort4*)&aggc[(size_t)node * DFEAT + c4] = ha;
  *(ushort4*)&aggt[(size_t)node * DFEAT + c4] = hb;
}

// ---------- fused K=256 GEMM: out = agg_c@Wc + agg_t@Wt + (bc+bt) [, relu] ----------
// Operand-SWAPPED mfma: A-operand = W^T frag, B-operand = agg frag.
// D layout then: lane holds out[row = row0+sub*16+(lane&15)][col = c8*16+(lane>>4)*4+u]
// -> 4 consecutive cols per lane -> packed ushort4 (8B) / float4 (16B) stores.
__global__ __launch_bounds__(256, 2) void gemmf_k(
    const ushort* __restrict__ ac, const ushort* __restrict__ at,
    const ushort* __restrict__ wTc, const ushort* __restrict__ wTt,
    const float* __restrict__ bc, const float* __restrict__ bt,
    float* __restrict__ outf, ushort* __restrict__ outh, int n, int last) {
  __shared__ __align__(16) ushort Bs[2][DFEAT * BPAD];
  __shared__ float bias[DFEAT];
  int tid = threadIdx.x;

#pragma unroll
  for (int it = 0; it < 8; it++) {
    int idx = tid + it * NT;          // 0..2047: 128 rows x 16 uint4
    int c = idx >> 4, i = idx & 15;
    *(uint4*)&Bs[0][c * BPAD + i * 8] = *(const uint4*)&wTc[c * DFEAT + i * 8];
    *(uint4*)&Bs[1][c * BPAD + i * 8] = *(const uint4*)&wTt[c * DFEAT + i * 8];
  }
  if (tid < DFEAT) bias[tid] = bc[tid] + bt[tid];
  __syncthreads();

  int wave = tid >> 6;
  int lane = tid & 63;
  int m = lane & 15;
  int q = lane >> 4;
  int row0 = blockIdx.x * GEMM_ROWS + wave * 32;
  int rowA = row0 + m;
  int rowB = row0 + 16 + m;

  f32x4 zero4 = {0.f, 0.f, 0.f, 0.f};
  f32x4 acc0[8], acc1[8];
#pragma unroll
  for (int i = 0; i < 8; i++) { acc0[i] = zero4; acc1[i] = zero4; }

#pragma unroll
  for (int ks = 0; ks < 8; ks++) {                 // K=256: 0..3 conv-half, 4..7 ctrl-half
    const ushort* A = (ks < 4) ? ac : at;
    const ushort* B = Bs[ks >> 2];
    int ko = (ks & 3) * 32 + q * 8;
    uint4 avA = make_uint4(0, 0, 0, 0), avB = make_uint4(0, 0, 0, 0);
    if (rowA < n) avA = *(const uint4*)&A[(size_t)rowA * DFEAT + ko];
    if (rowB < n) avB = *(const uint4*)&A[(size_t)rowB * DFEAT + ko];
    union { uint4 u; s8v s; } uA, uB; uA.u = avA; uB.u = avB;
#pragma unroll
    for (int c8 = 0; c8 < 8; c8++) {
      s8v bf = *(const s8v*)&B[(c8 * 16 + m) * BPAD + ko];
      acc0[c8] = __builtin_amdgcn_mfma_f32_16x16x32_bf16(bf, uA.s, acc0[c8], 0, 0, 0);
      acc1[c8] = __builtin_amdgcn_mfma_f32_16x16x32_bf16(bf, uB.s, acc1[c8], 0, 0, 0);
    }
  }

#pragma unroll
  for (int sub = 0; sub < 2; sub++) {
    int orow = row0 + sub * 16 + m;
    if (orow < n) {
#pragma unroll
      for (int c8 = 0; c8 < 8; c8++) {
        f32x4 a = sub ? acc1[c8] : acc0[c8];
        int col = c8 * 16 + q * 4;
        float4 bv = *(const float4*)&bias[col];
        float o0 = a[0] + bv.x, o1 = a[1] + bv.y, o2 = a[2] + bv.z, o3 = a[3] + bv.w;
        if (last) {
          *(float4*)&outf[(size_t)orow * DFEAT + col] = make_float4(o0, o1, o2, o3);
        } else {
          ushort4 h;
          h.x = f2bf(fmaxf(o0, 0.f));
          h.y = f2bf(fmaxf(o1, 0.f));
          h.z = f2bf(fmaxf(o2, 0.f));
          h.w = f2bf(fmaxf(o3, 0.f));
          *(ushort4*)&outh[(size_t)orow * DFEAT + col] = h;
        }
      }
    }
  }
}

extern "C" void kernel_launch(void* const* d_in, const int* in_sizes, int n_in,
                              void* d_out, int out_size, void* d_ws, size_t ws_size,
                              hipStream_t stream) {
  const float* x0 = (const float*)d_in[0];
  const int*   ei = (const int*)d_in[1];
  const int*   ci = (const int*)d_in[2];
  const float* Wc = (const float*)d_in[3];
  const float* bc = (const float*)d_in[4];
  const float* Wt = (const float*)d_in[5];
  const float* bt = (const float*)d_in[6];
  float* out = (float*)d_out;

  int n  = in_sizes[0] / DFEAT;     // 100000
  int E  = in_sizes[1] / 2;         // 600000
  int EC = in_sizes[2] / 2;         // 200000

  const int* e_src = ei;
  const int* e_dst = ei + E;
  const int* c_src = ci;
  const int* c_dst = ci + EC;

  char* p = (char*)d_ws;
  ushort* agg_c = (ushort*)p; p += (size_t)n * DFEAT * 2;
  ushort* agg_t = (ushort*)p; p += (size_t)n * DFEAT * 2;
  ushort* xh  = (ushort*)p; p += (size_t)n * DFEAT * 2;
  ushort* wT  = (ushort*)p; p += (size_t)8 * DFEAT * DFEAT * 2;
  float* dinv_c = (float*)p; p += (size_t)n * 4;
  float* dinv_t = (float*)p; p += (size_t)n * 4;
  int* cnt_c = (int*)p; p += (size_t)n * 4;
  int* cnt_t = (int*)p; p += (size_t)n * 4;
  int* rp_c  = (int*)p; p += (size_t)(n + 1) * 4;
  int* rp_t  = (int*)p; p += (size_t)(n + 1) * 4;
  int* csr_c = (int*)p; p += (size_t)E * 4;
  int* csr_t = (int*)p; p += (size_t)EC * 4;
  int* bsum  = (int*)p;

  int nb_n    = (n + NT - 1) / NT;
  int nb_node = (n + 7) / 8;
  int nb_gemm = (n + GEMM_ROWS - 1) / GEMM_ROWS;
  int nb_scan = (n + SCAN_ELEMS - 1) / SCAN_ELEMS;

  // ---- build CSR + dinv once per launch ----
  zero_k<<<(2 * n + NT - 1) / NT, NT, 0, stream>>>(cnt_c, 2 * n);
  hist2_k<<<(E + EC + NT - 1) / NT, NT, 0, stream>>>(e_dst, E, c_dst, EC, cnt_c, cnt_t);
  scan_partial_k<<<2 * nb_scan, NT, 0, stream>>>(cnt_c, cnt_t, n, bsum, nb_scan);
  scan_offsets_k<<<2, NT, 0, stream>>>(bsum, nb_scan, nb_scan, rp_c, rp_t, n);
  scan_final_k<<<2 * nb_scan, NT, 0, stream>>>(cnt_c, cnt_t, n, bsum, nb_scan, rp_c, rp_t);
  fill2_k<<<(E + EC + NT - 1) / NT, NT, 0, stream>>>(e_src, e_dst, E, c_src, c_dst, EC,
                                                     rp_c, cnt_c, csr_c, rp_t, cnt_t, csr_t);
  dinv_k<<<nb_n, NT, 0, stream>>>(rp_c, dinv_c, rp_t, dinv_t, n);

  // ---- bf16 conversions ----
  convx_k<<<(n * 32 + NT - 1) / NT, NT, 0, stream>>>(x0, xh, n * 32);
  convw_k<<<(8 * DFEAT * DFEAT) / NT, NT, 0, stream>>>(Wc, Wt, wT);

  // ---- layers: aggregate-first (shared-x gather), then single fused K=256 GEMM ----
  for (int i = 0; i < 4; i++) {
    aggregate2_k<<<nb_node, NT, 0, stream>>>(xh, rp_c, csr_c, rp_t, csr_t,
                                             dinv_c, dinv_t, agg_c, agg_t, n);
    gemmf_k<<<nb_gemm, NT, 0, stream>>>(agg_c, agg_t,
                                        wT + (size_t)i * DFEAT * DFEAT,
                                        wT + (size_t)(4 + i) * DFEAT * DFEAT,
                                        bc + i * DFEAT, bt + i * DFEAT,
                                        out, xh, n, (i == 3) ? 1 : 0);
  }
}